// Round 5
// baseline (369.455 us; speedup 1.0000x reference)
//
#include <hip/hip_runtime.h>

typedef unsigned short u16;
typedef __attribute__((ext_vector_type(8))) short short8;
typedef __attribute__((ext_vector_type(4))) float f32x4;
typedef __attribute__((ext_vector_type(4))) unsigned int u32x4;

union V8 { u32x4 u; short8 s; };

// ---------- helpers ----------
__device__ __forceinline__ u16 f2bf(float f) {
  union { float f; unsigned u; } v; v.f = f;
  unsigned r = v.u + 0x7fffu + ((v.u >> 16) & 1u);   // RNE
  return (u16)(r >> 16);
}

__device__ __forceinline__ unsigned cvt_pk_bf16(float lo, float hi) {
  unsigned r;
  asm("v_cvt_pk_bf16_f32 %0, %1, %2" : "=v"(r) : "v"(lo), "v"(hi));
  return r;
}

__device__ __forceinline__ void gload_lds16(const void* g, void* l) {
  __builtin_amdgcn_global_load_lds((const __attribute__((address_space(1))) unsigned int*)g,
                                   (__attribute__((address_space(3))) unsigned int*)l, 16, 0, 0);
}

__device__ __forceinline__ f32x4 mfma16(short8 a, short8 b, f32x4 c) {
  return __builtin_amdgcn_mfma_f32_16x16x32_bf16(a, b, c, 0, 0, 0);
}

// ---------- W[K][N] f32 -> Wt[N][K] bf16, 4 weights fused ----------
__global__ __launch_bounds__(256) void wtrans4_kernel(const float* __restrict__ Wq, const float* __restrict__ Wk,
                                                      const float* __restrict__ Wv, const float* __restrict__ Wo,
                                                      u16* __restrict__ WtQ, u16* __restrict__ WtK,
                                                      u16* __restrict__ WtV, u16* __restrict__ WtO) {
  const int bid = blockIdx.x;
  const int wsel = bid >> 9;
  const float* W = (wsel == 0) ? Wq : (wsel == 1) ? Wk : (wsel == 2) ? Wv : Wo;
  u16* Wt = (wsel == 0) ? WtQ : (wsel == 1) ? WtK : (wsel == 2) ? WtV : WtO;
  const int tid = (bid & 511) * 256 + threadIdx.x;
  const int n = tid & 1023;
  const int kb = (tid >> 10) << 3;
  u32x4 w;
#pragma unroll
  for (int j = 0; j < 4; j++)
    w[j] = cvt_pk_bf16(W[(size_t)(kb + 2 * j) * 1024 + n], W[(size_t)(kb + 2 * j + 1) * 1024 + n]);
  *(u32x4*)(Wt + (size_t)n * 1024 + kb) = w;
}

// ---------- merged QKV GEMM with fused f32->bf16 A conversion ----------
// A sections read DIRECTLY from query/key/value f32. 128x128 tile, BK=32, 4 waves,
// double-buffered LDS. A staged via reg (f32 load -> cvt_pk -> ds_write_b128 into the
// same swizzled slots gload_lds would fill); B (bf16 Wt) staged via global_load_lds.
// sec 0: bf16 out scaled by qscale. sec 1: bf16 out. sec 2: per-head transposed +
// kk-permuted Vt[B][H][64][2048].
__global__ __launch_bounds__(256) void gemm_qkv_kernel(const float* __restrict__ Aq,
                                                       const float* __restrict__ Ak,
                                                       const float* __restrict__ Av,
                                                       const u16* __restrict__ Wt,
                                                       const float* __restrict__ bq,
                                                       const float* __restrict__ bk,
                                                       const float* __restrict__ bv,
                                                       u16* __restrict__ Outs,
                                                       float qscale) {
  constexpr int K = 1024;
  __shared__ u16 Ash[2][4096];
  __shared__ u16 Bsh[2][4096];
  const int t = threadIdx.x;
  const int l = t & 63;
  const int w = t >> 6;
  const int wm = w >> 1, wn = w & 1;
  const int bid0 = blockIdx.x;
  const int swz = (bid0 & 7) * 192 + (bid0 >> 3);   // XCD-bijective, 1536 = 8*192
  const int bm = swz >> 3, bn = swz & 7;
  const int sec = bm >> 6;
  const int m0 = (bm & 63) * 128, n0 = bn * 128;
  const float* Asrc = (sec == 0) ? Aq : (sec == 1) ? Ak : Av;
  const u16* Bb = Wt + ((size_t)sec << 20) + (size_t)n0 * K;

  f32x4 acc[4][4];
#pragma unroll
  for (int i = 0; i < 4; i++)
#pragma unroll
    for (int j = 0; j < 4; j++) acc[i][j] = (f32x4){0.f, 0.f, 0.f, 0.f};

  // staging map (chunk swizzle; slot (line, c8) holds global (row, kchunk))
  const int line0 = t >> 3, c8 = t & 7;
  const int lc0 = c8 ^ (line0 & 7);
  const int row0 = 2 * line0 + (lc0 >> 2);
  const int kc0 = (lc0 & 3) << 3;
  const int line1 = line0 + 32;
  const int lc1 = c8 ^ (line1 & 7);
  const int row1 = 2 * line1 + (lc1 >> 2);
  const int kc1 = (lc1 & 3) << 3;

  const float* A0 = Asrc + (size_t)(m0 + row0) * K + kc0;
  const float* A1 = Asrc + (size_t)(m0 + row1) * K + kc1;

  int aoff[4], boff[4];
#pragma unroll
  for (int mt = 0; mt < 4; mt++) {
    int R = wm * 64 + mt * 16 + (l & 15);
    int cc = (((R & 1) << 2) + (l >> 4)) ^ ((R >> 1) & 7);
    aoff[mt] = (R >> 1) * 64 + cc * 8;
  }
#pragma unroll
  for (int nt = 0; nt < 4; nt++) {
    int R = wn * 64 + nt * 16 + (l & 15);
    int cc = (((R & 1) << 2) + (l >> 4)) ^ ((R >> 1) & 7);
    boff[nt] = (R >> 1) * 64 + cc * 8;
  }

  float4 La0, La1, La2, La3;
  auto loadA = [&](int k0) {
    La0 = *(const float4*)(A0 + k0);
    La1 = *(const float4*)(A0 + k0 + 4);
    La2 = *(const float4*)(A1 + k0);
    La3 = *(const float4*)(A1 + k0 + 4);
  };
  auto writeA = [&](int buf) {
    u32x4 w0, w1;
    w0[0] = cvt_pk_bf16(La0.x, La0.y); w0[1] = cvt_pk_bf16(La0.z, La0.w);
    w0[2] = cvt_pk_bf16(La1.x, La1.y); w0[3] = cvt_pk_bf16(La1.z, La1.w);
    w1[0] = cvt_pk_bf16(La2.x, La2.y); w1[1] = cvt_pk_bf16(La2.z, La2.w);
    w1[2] = cvt_pk_bf16(La3.x, La3.y); w1[3] = cvt_pk_bf16(La3.z, La3.w);
    *(u32x4*)&Ash[buf][t * 8] = w0;
    *(u32x4*)&Ash[buf][2048 + t * 8] = w1;
  };
  auto stB = [&](int buf, int k0) {
    u16* BW = &Bsh[buf][w * 512];
    gload_lds16(Bb + (size_t)row0 * K + k0 + kc0, BW);
    gload_lds16(Bb + (size_t)row1 * K + k0 + kc1, BW + 2048);
  };

  // prologue
  loadA(0);
  stB(0, 0);
  writeA(0);
  __syncthreads();

  int cur = 0;
  for (int k0 = 0; k0 < K; k0 += 32) {
    const bool nxt = (k0 + 32 < K);
    if (nxt) { loadA(k0 + 32); stB(cur ^ 1, k0 + 32); }
    short8 af[4], bfr[4];
#pragma unroll
    for (int mt = 0; mt < 4; mt++) af[mt] = *(const short8*)&Ash[cur][aoff[mt]];
#pragma unroll
    for (int nt = 0; nt < 4; nt++) bfr[nt] = *(const short8*)&Bsh[cur][boff[nt]];
    __builtin_amdgcn_s_setprio(1);
#pragma unroll
    for (int mt = 0; mt < 4; mt++)
#pragma unroll
      for (int nt = 0; nt < 4; nt++)
        acc[mt][nt] = mfma16(af[mt], bfr[nt], acc[mt][nt]);
    __builtin_amdgcn_s_setprio(0);
    if (nxt) writeA(cur ^ 1);
    __syncthreads();
    cur ^= 1;
  }

  // epilogue
#pragma unroll
  for (int nt = 0; nt < 4; nt++) {
    const int n = n0 + wn * 64 + nt * 16 + (l & 15);
    const float bias = (sec == 0) ? bq[n] : (sec == 1) ? bk[n] : bv[n];
    if (sec < 2) {
      const float outscale = (sec == 0) ? qscale : 1.0f;
      u16* C = Outs + ((size_t)sec << 23);
#pragma unroll
      for (int mt = 0; mt < 4; mt++) {
        const int m = m0 + wm * 64 + mt * 16 + ((l >> 4) << 2);
#pragma unroll
        for (int r = 0; r < 4; r++)
          C[(size_t)(m + r) * 1024 + n] = f2bf((acc[mt][nt][r] + bias) * outscale);
      }
    } else {
      const int b2 = m0 >> 11;
      const int h2 = n >> 6, d = n & 63;
      u16* C = Outs + ((size_t)2 << 23);
#pragma unroll
      for (int mt = 0; mt < 4; mt++) {
        const int s0 = (m0 & 2047) + wm * 64 + mt * 16 + ((l >> 4) << 2);
        const int u = s0 & 63;
        // kk-permutation: pos = (gg + 4*(c2>>1))*8 + (c2&1)*4 + j
        const int pos = ((((u >> 2) & 3) + ((u >> 5) & 1) * 4) << 3) + ((u >> 4) & 1) * 4;
        const int sp = (s0 & ~63) + pos;
        ushort4 pk;
        pk.x = f2bf(acc[mt][nt][0] + bias);
        pk.y = f2bf(acc[mt][nt][1] + bias);
        pk.z = f2bf(acc[mt][nt][2] + bias);
        pk.w = f2bf(acc[mt][nt][3] + bias);
        *(ushort4*)(C + (((size_t)((b2 * 16 + h2) * 64 + d)) << 11) + sp) = pk;
      }
    }
  }
}

// ---------- output GEMM: out[8192x1024] f32 = AO * WtO^T + bo ----------
__global__ __launch_bounds__(256) void gemm_out_kernel(const u16* __restrict__ A,
                                                       const u16* __restrict__ Bt,
                                                       const float* __restrict__ bias,
                                                       float* __restrict__ Cout) {
  constexpr int K = 1024;
  __shared__ u16 Ash[2][4096];
  __shared__ u16 Bsh[2][4096];
  const int t = threadIdx.x;
  const int l = t & 63;
  const int w = t >> 6;
  const int wm = w >> 1, wn = w & 1;
  const int bid0 = blockIdx.x;
  const int swz = (bid0 & 7) * 64 + (bid0 >> 3);    // 512 = 8*64
  const int bm = swz >> 3, bn = swz & 7;
  const int m0 = bm * 128, n0 = bn * 128;

  f32x4 acc[4][4];
#pragma unroll
  for (int i = 0; i < 4; i++)
#pragma unroll
    for (int j = 0; j < 4; j++) acc[i][j] = (f32x4){0.f, 0.f, 0.f, 0.f};

  const int line0 = t >> 3, c8 = t & 7;
  const int lc0 = c8 ^ (line0 & 7);
  const int row0 = 2 * line0 + (lc0 >> 2);
  const int kc0 = (lc0 & 3) << 3;
  const int line1 = line0 + 32;
  const int lc1 = c8 ^ (line1 & 7);
  const int row1 = 2 * line1 + (lc1 >> 2);
  const int kc1 = (lc1 & 3) << 3;

  const u16* Ab = A + (size_t)m0 * K;
  const u16* Bb = Bt + (size_t)n0 * K;

  int aoff[4], boff[4];
#pragma unroll
  for (int mt = 0; mt < 4; mt++) {
    int R = wm * 64 + mt * 16 + (l & 15);
    int cc = (((R & 1) << 2) + (l >> 4)) ^ ((R >> 1) & 7);
    aoff[mt] = (R >> 1) * 64 + cc * 8;
  }
#pragma unroll
  for (int nt = 0; nt < 4; nt++) {
    int R = wn * 64 + nt * 16 + (l & 15);
    int cc = (((R & 1) << 2) + (l >> 4)) ^ ((R >> 1) & 7);
    boff[nt] = (R >> 1) * 64 + cc * 8;
  }

  auto stage = [&](int buf, int k0) {
    u16* AW = &Ash[buf][w * 512];
    u16* BW = &Bsh[buf][w * 512];
    gload_lds16(Ab + (size_t)row0 * K + k0 + kc0, AW);
    gload_lds16(Ab + (size_t)row1 * K + k0 + kc1, AW + 2048);
    gload_lds16(Bb + (size_t)row0 * K + k0 + kc0, BW);
    gload_lds16(Bb + (size_t)row1 * K + k0 + kc1, BW + 2048);
  };

  stage(0, 0);
  __syncthreads();
  int cur = 0;
  for (int k0 = 0; k0 < K; k0 += 32) {
    if (k0 + 32 < K) stage(cur ^ 1, k0 + 32);
    short8 af[4], bfr[4];
#pragma unroll
    for (int mt = 0; mt < 4; mt++) af[mt] = *(const short8*)&Ash[cur][aoff[mt]];
#pragma unroll
    for (int nt = 0; nt < 4; nt++) bfr[nt] = *(const short8*)&Bsh[cur][boff[nt]];
    __builtin_amdgcn_s_setprio(1);
#pragma unroll
    for (int mt = 0; mt < 4; mt++)
#pragma unroll
      for (int nt = 0; nt < 4; nt++)
        acc[mt][nt] = mfma16(af[mt], bfr[nt], acc[mt][nt]);
    __builtin_amdgcn_s_setprio(0);
    __syncthreads();
    cur ^= 1;
  }

#pragma unroll
  for (int nt = 0; nt < 4; nt++) {
    const int n = n0 + wn * 64 + nt * 16 + (l & 15);
    const float bv2 = bias[n];
#pragma unroll
    for (int mt = 0; mt < 4; mt++) {
      const int m = m0 + wm * 64 + mt * 16 + ((l >> 4) << 2);
#pragma unroll
      for (int r = 0; r < 4; r++)
        Cout[(size_t)(m + r) * 1024 + n] = acc[mt][nt][r] + bv2;
    }
  }
}

// ---------- no-max softmax pack for one 16-q half ----------
__device__ __forceinline__ void pack_half(const f32x4 (&s)[4], short8& pa0, short8& pa1) {
  float p[4][4];
#pragma unroll
  for (int c = 0; c < 4; c++)
#pragma unroll
    for (int r = 0; r < 4; r++) p[c][r] = __builtin_amdgcn_exp2f(s[c][r]);
  V8 u0, u1;
  u0.u[0] = cvt_pk_bf16(p[0][0], p[0][1]); u0.u[1] = cvt_pk_bf16(p[0][2], p[0][3]);
  u0.u[2] = cvt_pk_bf16(p[1][0], p[1][1]); u0.u[3] = cvt_pk_bf16(p[1][2], p[1][3]);
  u1.u[0] = cvt_pk_bf16(p[2][0], p[2][1]); u1.u[1] = cvt_pk_bf16(p[2][2], p[2][3]);
  u1.u[2] = cvt_pk_bf16(p[3][0], p[3][1]); u1.u[3] = cvt_pk_bf16(p[3][2], p[3][3]);
  pa0 = u0.s; pa1 = u1.s;
}

// ---------- flash attention: 64 q per wave (4 halves), ones-MFMA row sums ----------
__global__ __launch_bounds__(256, 2) void attn_kernel(const u16* __restrict__ Qb,
                                                      const u16* __restrict__ Kb,
                                                      const u16* __restrict__ Vtb,
                                                      u16* __restrict__ AO) {
  __shared__ u16 Ksh[2][4096];   // [64 kk][64 d], chunk-swizzled
  __shared__ u16 Vsh[2][4096];   // [64 d][64 kk-permuted], chunk-swizzled
  const int t = threadIdx.x, l = t & 63, w = t >> 6;
  const int g = l >> 4, ql = l & 15;
  const int bid0 = blockIdx.x;
  const int bid = (bid0 & 7) * 64 + (bid0 >> 3);   // XCD swizzle, 512 = 8*64
  const int qt = bid & 7;
  const int bh = bid >> 3;
  const int h = bh & 15, b = bh >> 4;
  const int q0 = qt * 256 + w * 64;

  // Q fragments per half (B-operand: col=q=ql, k=d=g*8+i)
  short8 qf[4][2];
#pragma unroll
  for (int hh = 0; hh < 4; hh++) {
    const u16* Qrow = Qb + ((size_t)b * 2048 + q0 + hh * 16 + ql) * 1024 + h * 64 + g * 8;
    qf[hh][0] = *(const short8*)(Qrow);
    qf[hh][1] = *(const short8*)(Qrow + 32);
  }

  f32x4 oacc[4][4];   // [half][dt]
  f32x4 lacc[4];      // [half] row-sum accumulators (ones-MFMA)
#pragma unroll
  for (int hh = 0; hh < 4; hh++) {
    lacc[hh] = (f32x4){0.f, 0.f, 0.f, 0.f};
#pragma unroll
    for (int dt = 0; dt < 4; dt++) oacc[hh][dt] = (f32x4){0.f, 0.f, 0.f, 0.f};
  }
  short8 ones;
#pragma unroll
  for (int i = 0; i < 8; i++) ones[i] = (short)0x3F80;   // bf16 1.0

  const int srow0 = t >> 3, sc = t & 7;
  const int slc0 = sc ^ (srow0 & 7);
  const int srow1 = srow0 + 32, slc1 = sc ^ (srow1 & 7);
  const u16* Kbase = Kb + ((size_t)b * 2048) * 1024 + h * 64;
  const u16* Vbase = Vtb + ((size_t)(b * 16 + h) * 64) * 2048;

  auto stage = [&](int buf, int kk0) {
    u16* KW = &Ksh[buf][w * 512];
    u16* VW = &Vsh[buf][w * 512];
    gload_lds16(Kbase + (size_t)(kk0 + srow0) * 1024 + slc0 * 8, KW);
    gload_lds16(Kbase + (size_t)(kk0 + srow1) * 1024 + slc1 * 8, KW + 2048);
    gload_lds16(Vbase + (size_t)srow0 * 2048 + kk0 + slc0 * 8, VW);
    gload_lds16(Vbase + (size_t)srow1 * 2048 + kk0 + slc1 * 8, VW + 2048);
  };

  int voff0[4], voff1[4];
#pragma unroll
  for (int dt = 0; dt < 4; dt++) {
    const int d = dt * 16 + ql;
    voff0[dt] = d * 64 + ((g ^ (d & 7)) << 3);
    voff1[dt] = d * 64 + (((g + 4) ^ (d & 7)) << 3);
  }

  stage(0, 0);
  __syncthreads();
  int cur = 0;

  for (int kk0 = 0; kk0 < 2048; kk0 += 64) {
    if (kk0 + 64 < 2048) stage(cur ^ 1, kk0 + 64);
    const u16* KC = Ksh[cur];
    const u16* VC = Vsh[cur];

    // swapped QK^T for 4 halves: kf reads amortized 4x
    f32x4 s[4][4];   // [half][c]
    __builtin_amdgcn_s_setprio(1);
#pragma unroll
    for (int c = 0; c < 4; c++) {
      const int R = c * 16 + ql;
      const int x = R & 7;
      const short8 kf0 = *(const short8*)&KC[R * 64 + ((g ^ x) << 3)];
      const short8 kf1 = *(const short8*)&KC[R * 64 + (((g + 4) ^ x) << 3)];
#pragma unroll
      for (int hh = 0; hh < 4; hh++) {
        f32x4 z = (f32x4){0.f, 0.f, 0.f, 0.f};
        z = mfma16(kf0, qf[hh][0], z);
        s[hh][c] = mfma16(kf1, qf[hh][1], z);
      }
    }
    __builtin_amdgcn_s_setprio(0);

    // softmax (no-max; scale folded into Q) + pack to bf16 A-fragments
    short8 pa[4][2];
#pragma unroll
    for (int hh = 0; hh < 4; hh++) pack_half(s[hh], pa[hh][0], pa[hh][1]);

    __builtin_amdgcn_s_setprio(1);
    // row sums via ones-MFMA (lands in accumulator row layout; kills epilogue shfls)
#pragma unroll
    for (int hh = 0; hh < 4; hh++) {
      lacc[hh] = mfma16(pa[hh][0], ones, lacc[hh]);
      lacc[hh] = mfma16(pa[hh][1], ones, lacc[hh]);
    }
    // PV: vf reads amortized 4x
#pragma unroll
    for (int dt = 0; dt < 4; dt++) {
      const short8 vf0 = *(const short8*)&VC[voff0[dt]];
      const short8 vf1 = *(const short8*)&VC[voff1[dt]];
#pragma unroll
      for (int hh = 0; hh < 4; hh++) {
        oacc[hh][dt] = mfma16(pa[hh][0], vf0, oacc[hh][dt]);
        oacc[hh][dt] = mfma16(pa[hh][1], vf1, oacc[hh][dt]);
      }
    }
    __builtin_amdgcn_s_setprio(0);
    __syncthreads();
    cur ^= 1;
  }

  // epilogue: normalize by lacc (already per-row, no shuffles) + store
#pragma unroll
  for (int hh = 0; hh < 4; hh++) {
    f32x4 inv;
#pragma unroll
    for (int r = 0; r < 4; r++) inv[r] = __builtin_amdgcn_rcpf(lacc[hh][r]);
    u16* Arow = AO + ((size_t)b * 2048 + q0 + hh * 16) * 1024 + h * 64;
#pragma unroll
    for (int dt = 0; dt < 4; dt++) {
      const int col = dt * 16 + ql;
#pragma unroll
      for (int r = 0; r < 4; r++)
        Arow[(size_t)(4 * g + r) * 1024 + col] = f2bf(oacc[hh][dt][r] * inv[r]);
    }
  }
}

// ---------- launch ----------
extern "C" void kernel_launch(void* const* d_in, const int* in_sizes, int n_in,
                              void* d_out, int out_size, void* d_ws, size_t ws_size,
                              hipStream_t stream) {
  (void)in_sizes; (void)n_in; (void)out_size; (void)ws_size;
  const float* query = (const float*)d_in[0];
  const float* key   = (const float*)d_in[1];
  const float* value = (const float*)d_in[2];
  const float* Wq = (const float*)d_in[3];  const float* bq = (const float*)d_in[4];
  const float* Wk = (const float*)d_in[5];  const float* bk = (const float*)d_in[6];
  const float* Wv = (const float*)d_in[7];  const float* bv = (const float*)d_in[8];
  const float* Wo = (const float*)d_in[9];  const float* bo = (const float*)d_in[10];
  float* out = (float*)d_out;

  const size_t SZX = (size_t)8192 * 1024;
  const size_t SZW = (size_t)1024 * 1024;
  u16* AO  = (u16*)d_ws;          // attention output bf16
  u16* Qb  = AO + SZX;            // projection outputs [Qb;Kbf;Vtb] consecutive
  u16* Kbf = Qb + SZX;
  u16* Vtb = Kbf + SZX;
  u16* WtQ = Vtb + SZX;           // weights [WtQ;WtK;WtV;WtO] consecutive
  u16* WtK = WtQ + SZW;
  u16* WtV = WtK + SZW;
  u16* WtO = WtV + SZW;

  const float QSCALE = 0.125f * 1.44269504088896f;   // 1/sqrt(64) * log2(e) folded into Q

  wtrans4_kernel<<<2048, 256, 0, stream>>>(Wq, Wk, Wv, Wo, WtQ, WtK, WtV, WtO);

  gemm_qkv_kernel<<<1536, 256, 0, stream>>>(query, key, value, WtQ, bq, bk, bv, Qb, QSCALE);

  attn_kernel<<<512, 256, 0, stream>>>(Qb, Kbf, Vtb, AO);

  gemm_out_kernel<<<512, 256, 0, stream>>>(AO, WtO, bo, out);
}

// Round 6
// 321.661 us; speedup vs baseline: 1.1486x; 1.1486x over previous
//
#include <hip/hip_runtime.h>

typedef unsigned short u16;
typedef __attribute__((ext_vector_type(8))) short short8;
typedef __attribute__((ext_vector_type(4))) float f32x4;
typedef __attribute__((ext_vector_type(4))) unsigned int u32x4;

union V8 { u32x4 u; short8 s; };

// ---------- helpers ----------
__device__ __forceinline__ u16 f2bf(float f) {
  union { float f; unsigned u; } v; v.f = f;
  unsigned r = v.u + 0x7fffu + ((v.u >> 16) & 1u);   // RNE
  return (u16)(r >> 16);
}

__device__ __forceinline__ unsigned cvt_pk_bf16(float lo, float hi) {
  unsigned r;
  asm("v_cvt_pk_bf16_f32 %0, %1, %2" : "=v"(r) : "v"(lo), "v"(hi));
  return r;
}

__device__ __forceinline__ void gload_lds16(const void* g, void* l) {
  __builtin_amdgcn_global_load_lds((const __attribute__((address_space(1))) unsigned int*)g,
                                   (__attribute__((address_space(3))) unsigned int*)l, 16, 0, 0);
}

__device__ __forceinline__ f32x4 mfma16(short8 a, short8 b, f32x4 c) {
  return __builtin_amdgcn_mfma_f32_16x16x32_bf16(a, b, c, 0, 0, 0);
}

// ---------- prep: f32->bf16 convert of q/k/v (+ 4 weight transposes), one kernel ----------
// blocks 0..12287: convert 8 f32 -> 8 bf16 per thread (q/k/v).
// blocks 12288..14335: transpose+convert weights W[K][N] f32 -> Wt[N][K] bf16.
__global__ __launch_bounds__(256) void prep_kernel(const float* __restrict__ q,
                                                   const float* __restrict__ k,
                                                   const float* __restrict__ v,
                                                   const float* __restrict__ Wq, const float* __restrict__ Wk,
                                                   const float* __restrict__ Wv, const float* __restrict__ Wo,
                                                   u16* __restrict__ oq, u16* __restrict__ ok, u16* __restrict__ ov,
                                                   u16* __restrict__ WtQ, u16* __restrict__ WtK,
                                                   u16* __restrict__ WtV, u16* __restrict__ WtO) {
  const int bid = blockIdx.x;
  if (bid < 12288) {
    const float* in = (bid < 4096) ? q : (bid < 8192 ? k : v);
    u16* out = (bid < 4096) ? oq : (bid < 8192 ? ok : ov);
    const size_t i = ((size_t)(bid & 4095) * 256 + threadIdx.x) * 8;
    const float4* p = (const float4*)(in + i);
    float4 a = p[0], b = p[1];
    u32x4 w;
    w[0] = cvt_pk_bf16(a.x, a.y); w[1] = cvt_pk_bf16(a.z, a.w);
    w[2] = cvt_pk_bf16(b.x, b.y); w[3] = cvt_pk_bf16(b.z, b.w);
    *(u32x4*)(out + i) = w;
  } else {
    const int wb = bid - 12288;
    const int wsel = wb >> 9;
    const float* W = (wsel == 0) ? Wq : (wsel == 1) ? Wk : (wsel == 2) ? Wv : Wo;
    u16* Wt = (wsel == 0) ? WtQ : (wsel == 1) ? WtK : (wsel == 2) ? WtV : WtO;
    const int tid = (wb & 511) * 256 + threadIdx.x;
    const int n = tid & 1023;
    const int kb = (tid >> 10) << 3;
    u32x4 w;
#pragma unroll
    for (int j = 0; j < 4; j++)
      w[j] = cvt_pk_bf16(W[(size_t)(kb + 2 * j) * 1024 + n], W[(size_t)(kb + 2 * j + 1) * 1024 + n]);
    *(u32x4*)(Wt + (size_t)n * 1024 + kb) = w;
  }
}

// ---------- merged QKV GEMM (round-3 proven structure) ----------
// A = [qin;kin;vin] stacked on M (24576x1024 bf16). Wt = [WtQ|WtK|WtV].
// 128x128 tile, BK=32, 4 waves, double-buffered LDS, global_load_lds both operands.
// sec 0: bf16 out scaled. sec 1: bf16 out. sec 2: per-head transposed + kk-permuted
// Vt[B][H][64][2048] (PV fragments become single b128 LDS reads in attention).
__global__ __launch_bounds__(256) void gemm_qkv_kernel(const u16* __restrict__ A,
                                                       const u16* __restrict__ Wt,
                                                       const float* __restrict__ bq,
                                                       const float* __restrict__ bk,
                                                       const float* __restrict__ bv,
                                                       u16* __restrict__ Outs,
                                                       float qscale) {
  constexpr int K = 1024;
  __shared__ u16 Ash[2][4096];
  __shared__ u16 Bsh[2][4096];
  const int t = threadIdx.x;
  const int l = t & 63;
  const int w = t >> 6;
  const int wm = w >> 1, wn = w & 1;
  const int bid0 = blockIdx.x;
  const int swz = (bid0 & 7) * 192 + (bid0 >> 3);   // XCD-bijective, 1536 = 8*192
  const int bm = swz >> 3, bn = swz & 7;
  const int m0 = bm * 128, n0 = bn * 128;
  const int sec = m0 >> 13;
  const u16* Bt = Wt + ((size_t)sec << 20);
  const float* bias = (sec == 0) ? bq : (sec == 1) ? bk : bv;
  const float outscale = (sec == 0) ? qscale : 1.0f;

  f32x4 acc[4][4];
#pragma unroll
  for (int i = 0; i < 4; i++)
#pragma unroll
    for (int j = 0; j < 4; j++) acc[i][j] = (f32x4){0.f, 0.f, 0.f, 0.f};

  const int line0 = t >> 3, c8 = t & 7;
  const int lc0 = c8 ^ (line0 & 7);
  const int row0 = 2 * line0 + (lc0 >> 2);
  const int kc0 = (lc0 & 3) << 3;
  const int line1 = line0 + 32;
  const int lc1 = c8 ^ (line1 & 7);
  const int row1 = 2 * line1 + (lc1 >> 2);
  const int kc1 = (lc1 & 3) << 3;

  const u16* Ab = A + (size_t)m0 * K;
  const u16* Bb = Bt + (size_t)n0 * K;

  int aoff[4], boff[4];
#pragma unroll
  for (int mt = 0; mt < 4; mt++) {
    int R = wm * 64 + mt * 16 + (l & 15);
    int cc = (((R & 1) << 2) + (l >> 4)) ^ ((R >> 1) & 7);
    aoff[mt] = (R >> 1) * 64 + cc * 8;
  }
#pragma unroll
  for (int nt = 0; nt < 4; nt++) {
    int R = wn * 64 + nt * 16 + (l & 15);
    int cc = (((R & 1) << 2) + (l >> 4)) ^ ((R >> 1) & 7);
    boff[nt] = (R >> 1) * 64 + cc * 8;
  }

  auto stage = [&](int buf, int k0) {
    u16* AW = &Ash[buf][w * 512];
    u16* BW = &Bsh[buf][w * 512];
    gload_lds16(Ab + (size_t)row0 * K + k0 + kc0, AW);
    gload_lds16(Ab + (size_t)row1 * K + k0 + kc1, AW + 2048);
    gload_lds16(Bb + (size_t)row0 * K + k0 + kc0, BW);
    gload_lds16(Bb + (size_t)row1 * K + k0 + kc1, BW + 2048);
  };

  stage(0, 0);
  __syncthreads();
  int cur = 0;
  for (int k0 = 0; k0 < K; k0 += 32) {
    if (k0 + 32 < K) stage(cur ^ 1, k0 + 32);
    short8 af[4], bfr[4];
#pragma unroll
    for (int mt = 0; mt < 4; mt++) af[mt] = *(const short8*)&Ash[cur][aoff[mt]];
#pragma unroll
    for (int nt = 0; nt < 4; nt++) bfr[nt] = *(const short8*)&Bsh[cur][boff[nt]];
#pragma unroll
    for (int mt = 0; mt < 4; mt++)
#pragma unroll
      for (int nt = 0; nt < 4; nt++)
        acc[mt][nt] = mfma16(af[mt], bfr[nt], acc[mt][nt]);
    __syncthreads();
    cur ^= 1;
  }

#pragma unroll
  for (int nt = 0; nt < 4; nt++) {
    const int n = n0 + wn * 64 + nt * 16 + (l & 15);
    const float bv2 = bias[n];
    if (sec < 2) {
      u16* C = Outs + ((size_t)sec << 23);
#pragma unroll
      for (int mt = 0; mt < 4; mt++) {
        const int m = (m0 & 8191) + wm * 64 + mt * 16 + ((l >> 4) << 2);
#pragma unroll
        for (int r = 0; r < 4; r++)
          C[(size_t)(m + r) * 1024 + n] = f2bf((acc[mt][nt][r] + bv2) * outscale);
      }
    } else {
      const int mloc = m0 & 8191;
      const int b2 = mloc >> 11;
      const int h2 = n >> 6, d = n & 63;
      u16* C = Outs + ((size_t)2 << 23);
#pragma unroll
      for (int mt = 0; mt < 4; mt++) {
        const int s0 = (mloc & 2047) + wm * 64 + mt * 16 + ((l >> 4) << 2);
        const int u = s0 & 63;
        // kk-permutation: pos = (gg + 4*(c2>>1))*8 + (c2&1)*4 + j
        const int pos = ((((u >> 2) & 3) + ((u >> 5) & 1) * 4) << 3) + ((u >> 4) & 1) * 4;
        const int sp = (s0 & ~63) + pos;
        ushort4 pk;
        pk.x = f2bf(acc[mt][nt][0] + bv2);
        pk.y = f2bf(acc[mt][nt][1] + bv2);
        pk.z = f2bf(acc[mt][nt][2] + bv2);
        pk.w = f2bf(acc[mt][nt][3] + bv2);
        *(ushort4*)(C + (((size_t)((b2 * 16 + h2) * 64 + d)) << 11) + sp) = pk;
      }
    }
  }
}

// ---------- output GEMM: out[8192x1024] f32 = AO * WtO^T + bo ----------
__global__ __launch_bounds__(256) void gemm_out_kernel(const u16* __restrict__ A,
                                                       const u16* __restrict__ Bt,
                                                       const float* __restrict__ bias,
                                                       float* __restrict__ Cout) {
  constexpr int K = 1024;
  __shared__ u16 Ash[2][4096];
  __shared__ u16 Bsh[2][4096];
  const int t = threadIdx.x;
  const int l = t & 63;
  const int w = t >> 6;
  const int wm = w >> 1, wn = w & 1;
  const int bid0 = blockIdx.x;
  const int swz = (bid0 & 7) * 64 + (bid0 >> 3);    // 512 = 8*64
  const int bm = swz >> 3, bn = swz & 7;
  const int m0 = bm * 128, n0 = bn * 128;

  f32x4 acc[4][4];
#pragma unroll
  for (int i = 0; i < 4; i++)
#pragma unroll
    for (int j = 0; j < 4; j++) acc[i][j] = (f32x4){0.f, 0.f, 0.f, 0.f};

  const int line0 = t >> 3, c8 = t & 7;
  const int lc0 = c8 ^ (line0 & 7);
  const int row0 = 2 * line0 + (lc0 >> 2);
  const int kc0 = (lc0 & 3) << 3;
  const int line1 = line0 + 32;
  const int lc1 = c8 ^ (line1 & 7);
  const int row1 = 2 * line1 + (lc1 >> 2);
  const int kc1 = (lc1 & 3) << 3;

  const u16* Ab = A + (size_t)m0 * K;
  const u16* Bb = Bt + (size_t)n0 * K;

  int aoff[4], boff[4];
#pragma unroll
  for (int mt = 0; mt < 4; mt++) {
    int R = wm * 64 + mt * 16 + (l & 15);
    int cc = (((R & 1) << 2) + (l >> 4)) ^ ((R >> 1) & 7);
    aoff[mt] = (R >> 1) * 64 + cc * 8;
  }
#pragma unroll
  for (int nt = 0; nt < 4; nt++) {
    int R = wn * 64 + nt * 16 + (l & 15);
    int cc = (((R & 1) << 2) + (l >> 4)) ^ ((R >> 1) & 7);
    boff[nt] = (R >> 1) * 64 + cc * 8;
  }

  auto stage = [&](int buf, int k0) {
    u16* AW = &Ash[buf][w * 512];
    u16* BW = &Bsh[buf][w * 512];
    gload_lds16(Ab + (size_t)row0 * K + k0 + kc0, AW);
    gload_lds16(Ab + (size_t)row1 * K + k0 + kc1, AW + 2048);
    gload_lds16(Bb + (size_t)row0 * K + k0 + kc0, BW);
    gload_lds16(Bb + (size_t)row1 * K + k0 + kc1, BW + 2048);
  };

  stage(0, 0);
  __syncthreads();
  int cur = 0;
  for (int k0 = 0; k0 < K; k0 += 32) {
    if (k0 + 32 < K) stage(cur ^ 1, k0 + 32);
    short8 af[4], bfr[4];
#pragma unroll
    for (int mt = 0; mt < 4; mt++) af[mt] = *(const short8*)&Ash[cur][aoff[mt]];
#pragma unroll
    for (int nt = 0; nt < 4; nt++) bfr[nt] = *(const short8*)&Bsh[cur][boff[nt]];
#pragma unroll
    for (int mt = 0; mt < 4; mt++)
#pragma unroll
      for (int nt = 0; nt < 4; nt++)
        acc[mt][nt] = mfma16(af[mt], bfr[nt], acc[mt][nt]);
    __syncthreads();
    cur ^= 1;
  }

#pragma unroll
  for (int nt = 0; nt < 4; nt++) {
    const int n = n0 + wn * 64 + nt * 16 + (l & 15);
    const float bv2 = bias[n];
#pragma unroll
    for (int mt = 0; mt < 4; mt++) {
      const int m = m0 + wm * 64 + mt * 16 + ((l >> 4) << 2);
#pragma unroll
      for (int r = 0; r < 4; r++)
        Cout[(size_t)(m + r) * 1024 + n] = acc[mt][nt][r] + bv2;
    }
  }
}

// ---------- no-max softmax pack for one 16-q half ----------
__device__ __forceinline__ void pack_half(const f32x4 (&s)[4], short8& pa0, short8& pa1) {
  float p[4][4];
#pragma unroll
  for (int c = 0; c < 4; c++)
#pragma unroll
    for (int r = 0; r < 4; r++) p[c][r] = __builtin_amdgcn_exp2f(s[c][r]);
  V8 u0, u1;
  u0.u[0] = cvt_pk_bf16(p[0][0], p[0][1]); u0.u[1] = cvt_pk_bf16(p[0][2], p[0][3]);
  u0.u[2] = cvt_pk_bf16(p[1][0], p[1][1]); u0.u[3] = cvt_pk_bf16(p[1][2], p[1][3]);
  u1.u[0] = cvt_pk_bf16(p[2][0], p[2][1]); u1.u[1] = cvt_pk_bf16(p[2][2], p[2][3]);
  u1.u[2] = cvt_pk_bf16(p[3][0], p[3][1]); u1.u[3] = cvt_pk_bf16(p[3][2], p[3][3]);
  pa0 = u0.s; pa1 = u1.s;
}

// ---------- flash attention: 64 q per wave (4 halves), ones-MFMA row sums ----------
__global__ __launch_bounds__(256, 2) void attn_kernel(const u16* __restrict__ Qb,
                                                      const u16* __restrict__ Kb,
                                                      const u16* __restrict__ Vtb,
                                                      u16* __restrict__ AO) {
  __shared__ u16 Ksh[2][4096];   // [64 kk][64 d], chunk-swizzled
  __shared__ u16 Vsh[2][4096];   // [64 d][64 kk-permuted], chunk-swizzled
  const int t = threadIdx.x, l = t & 63, w = t >> 6;
  const int g = l >> 4, ql = l & 15;
  const int bid0 = blockIdx.x;
  const int bid = (bid0 & 7) * 64 + (bid0 >> 3);   // XCD swizzle, 512 = 8*64
  const int qt = bid & 7;
  const int bh = bid >> 3;
  const int h = bh & 15, b = bh >> 4;
  const int q0 = qt * 256 + w * 64;

  // Q fragments per half (B-operand: col=q=ql, k=d=g*8+i)
  short8 qf[4][2];
#pragma unroll
  for (int hh = 0; hh < 4; hh++) {
    const u16* Qrow = Qb + ((size_t)b * 2048 + q0 + hh * 16 + ql) * 1024 + h * 64 + g * 8;
    qf[hh][0] = *(const short8*)(Qrow);
    qf[hh][1] = *(const short8*)(Qrow + 32);
  }

  f32x4 oacc[4][4];   // [half][dt]
  f32x4 lacc[4];      // [half] row-sum accumulators (ones-MFMA)
#pragma unroll
  for (int hh = 0; hh < 4; hh++) {
    lacc[hh] = (f32x4){0.f, 0.f, 0.f, 0.f};
#pragma unroll
    for (int dt = 0; dt < 4; dt++) oacc[hh][dt] = (f32x4){0.f, 0.f, 0.f, 0.f};
  }
  short8 ones;
#pragma unroll
  for (int i = 0; i < 8; i++) ones[i] = (short)0x3F80;   // bf16 1.0

  const int srow0 = t >> 3, sc = t & 7;
  const int slc0 = sc ^ (srow0 & 7);
  const int srow1 = srow0 + 32, slc1 = sc ^ (srow1 & 7);
  const u16* Kbase = Kb + ((size_t)b * 2048) * 1024 + h * 64;
  const u16* Vbase = Vtb + ((size_t)(b * 16 + h) * 64) * 2048;

  auto stage = [&](int buf, int kk0) {
    u16* KW = &Ksh[buf][w * 512];
    u16* VW = &Vsh[buf][w * 512];
    gload_lds16(Kbase + (size_t)(kk0 + srow0) * 1024 + slc0 * 8, KW);
    gload_lds16(Kbase + (size_t)(kk0 + srow1) * 1024 + slc1 * 8, KW + 2048);
    gload_lds16(Vbase + (size_t)srow0 * 2048 + kk0 + slc0 * 8, VW);
    gload_lds16(Vbase + (size_t)srow1 * 2048 + kk0 + slc1 * 8, VW + 2048);
  };

  int voff0[4], voff1[4];
#pragma unroll
  for (int dt = 0; dt < 4; dt++) {
    const int d = dt * 16 + ql;
    voff0[dt] = d * 64 + ((g ^ (d & 7)) << 3);
    voff1[dt] = d * 64 + (((g + 4) ^ (d & 7)) << 3);
  }

  stage(0, 0);
  __syncthreads();
  int cur = 0;

  for (int kk0 = 0; kk0 < 2048; kk0 += 64) {
    if (kk0 + 64 < 2048) stage(cur ^ 1, kk0 + 64);
    const u16* KC = Ksh[cur];
    const u16* VC = Vsh[cur];

    // swapped QK^T for 4 halves: kf reads amortized 4x
    f32x4 s[4][4];   // [half][c]
    __builtin_amdgcn_s_setprio(1);
#pragma unroll
    for (int c = 0; c < 4; c++) {
      const int R = c * 16 + ql;
      const int x = R & 7;
      const short8 kf0 = *(const short8*)&KC[R * 64 + ((g ^ x) << 3)];
      const short8 kf1 = *(const short8*)&KC[R * 64 + (((g + 4) ^ x) << 3)];
#pragma unroll
      for (int hh = 0; hh < 4; hh++) {
        f32x4 z = (f32x4){0.f, 0.f, 0.f, 0.f};
        z = mfma16(kf0, qf[hh][0], z);
        s[hh][c] = mfma16(kf1, qf[hh][1], z);
      }
    }
    __builtin_amdgcn_s_setprio(0);

    // softmax (no-max; scale folded into Q) + pack to bf16 A-fragments
    short8 pa[4][2];
#pragma unroll
    for (int hh = 0; hh < 4; hh++) pack_half(s[hh], pa[hh][0], pa[hh][1]);

    __builtin_amdgcn_s_setprio(1);
    // row sums via ones-MFMA (lands in accumulator row layout; kills epilogue shfls)
#pragma unroll
    for (int hh = 0; hh < 4; hh++) {
      lacc[hh] = mfma16(pa[hh][0], ones, lacc[hh]);
      lacc[hh] = mfma16(pa[hh][1], ones, lacc[hh]);
    }
    // PV: vf reads amortized 4x
#pragma unroll
    for (int dt = 0; dt < 4; dt++) {
      const short8 vf0 = *(const short8*)&VC[voff0[dt]];
      const short8 vf1 = *(const short8*)&VC[voff1[dt]];
#pragma unroll
      for (int hh = 0; hh < 4; hh++) {
        oacc[hh][dt] = mfma16(pa[hh][0], vf0, oacc[hh][dt]);
        oacc[hh][dt] = mfma16(pa[hh][1], vf1, oacc[hh][dt]);
      }
    }
    __builtin_amdgcn_s_setprio(0);
    __syncthreads();
    cur ^= 1;
  }

  // epilogue: normalize by lacc (already per-row, no shuffles) + store
#pragma unroll
  for (int hh = 0; hh < 4; hh++) {
    f32x4 inv;
#pragma unroll
    for (int r = 0; r < 4; r++) inv[r] = __builtin_amdgcn_rcpf(lacc[hh][r]);
    u16* Arow = AO + ((size_t)b * 2048 + q0 + hh * 16) * 1024 + h * 64;
#pragma unroll
    for (int dt = 0; dt < 4; dt++) {
      const int col = dt * 16 + ql;
#pragma unroll
      for (int r = 0; r < 4; r++)
        Arow[(size_t)(4 * g + r) * 1024 + col] = f2bf(oacc[hh][dt][r] * inv[r]);
    }
  }
}

// ---------- launch ----------
extern "C" void kernel_launch(void* const* d_in, const int* in_sizes, int n_in,
                              void* d_out, int out_size, void* d_ws, size_t ws_size,
                              hipStream_t stream) {
  (void)in_sizes; (void)n_in; (void)out_size; (void)ws_size;
  const float* query = (const float*)d_in[0];
  const float* key   = (const float*)d_in[1];
  const float* value = (const float*)d_in[2];
  const float* Wq = (const float*)d_in[3];  const float* bq = (const float*)d_in[4];
  const float* Wk = (const float*)d_in[5];  const float* bk = (const float*)d_in[6];
  const float* Wv = (const float*)d_in[7];  const float* bv = (const float*)d_in[8];
  const float* Wo = (const float*)d_in[9];  const float* bo = (const float*)d_in[10];
  float* out = (float*)d_out;

  const size_t SZX = (size_t)8192 * 1024;
  const size_t SZW = (size_t)1024 * 1024;
  u16* qin = (u16*)d_ws;          // A-stack base: [qin;kin;vin]
  u16* kin = qin + SZX;
  u16* vin = kin + SZX;
  u16* Qb  = vin + SZX;           // projection outputs [Qb;Kbf;Vtb] consecutive
  u16* Kbf = Qb + SZX;
  u16* Vtb = Kbf + SZX;
  u16* WtQ = Vtb + SZX;           // weights [WtQ;WtK;WtV;WtO] consecutive
  u16* WtK = WtQ + SZW;
  u16* WtV = WtK + SZW;
  u16* WtO = WtV + SZW;
  u16* AO  = qin;                 // reuse (dead after QKV GEMM)

  const float QSCALE = 0.125f * 1.44269504088896f;   // 1/sqrt(64) * log2(e) folded into Q

  prep_kernel<<<14336, 256, 0, stream>>>(query, key, value, Wq, Wk, Wv, Wo,
                                         qin, kin, vin, WtQ, WtK, WtV, WtO);

  gemm_qkv_kernel<<<1536, 256, 0, stream>>>(qin, WtQ, bq, bk, bv, Qb, QSCALE);

  attn_kernel<<<512, 256, 0, stream>>>(Qb, Kbf, Vtb, AO);

  gemm_out_kernel<<<512, 256, 0, stream>>>(AO, WtO, bo, out);
}